// Round 3
// baseline (1623.217 us; speedup 1.0000x reference)
//
#include <hip/hip_runtime.h>
#include <stdint.h>

#define KOFF 27
#define CIN 64
#define COUT 128
#define EPS 1e-5f

using frag_ab = __attribute__((ext_vector_type(8))) short;
using frag_cd = __attribute__((ext_vector_type(4))) float;

__device__ __forceinline__ float bf2f(unsigned short u) {
  union { unsigned int i; float f; } x; x.i = ((unsigned int)u) << 16; return x.f;
}
__device__ __forceinline__ unsigned short f2bf(float f) {
  union { float f; unsigned int i; } x; x.f = f;
  unsigned int u = x.i;
  u += 0x7fffu + ((u >> 16) & 1u);   // round-to-nearest-even
  return (unsigned short)(u >> 16);
}
__device__ __forceinline__ uint4 pack_bf16(uint4 lo, uint4 hi) {
  union { uint4 u; float f[4]; } a, b; a.u = lo; b.u = hi;
  uint4 r;
  r.x = (unsigned)f2bf(a.f[0]) | ((unsigned)f2bf(a.f[1]) << 16);
  r.y = (unsigned)f2bf(a.f[2]) | ((unsigned)f2bf(a.f[3]) << 16);
  r.z = (unsigned)f2bf(b.f[0]) | ((unsigned)f2bf(b.f[1]) << 16);
  r.w = (unsigned)f2bf(b.f[2]) | ((unsigned)f2bf(b.f[3]) << 16);
  return r;
}

// ---------------------------------------------------------------------------
// Pipelined gather-GEMM: Y[row] = sum_k X[nbr[k][row]] @ W[k].
// X fp32 (XF32) or bf16; Wt pre-transposed bf16 [k][co][ci]; Y bf16 or fp32.
// BLOCK 128x128, 256 thr = 4 waves (2x2 of 64x64/wave), BK=64 chunks.
// Software pipeline: regs prefetch chunk t+1 during MFMA(t); rulebook idx
// prefetched one full ko ahead. XOR-swizzled LDS (LDA=64, seg^=row&7):
// ds_write_b128 and ds_read_b128 both 2-way (free) instead of 8-way.
// ---------------------------------------------------------------------------
template <int CI, bool GATHER, bool XF32, bool OF32>
__global__ __launch_bounds__(256, XF32 ? 2 : 3) void conv_kernel(
    const void* __restrict__ Xv, const int* __restrict__ nbr,
    const unsigned short* __restrict__ Wt, void* __restrict__ Yv,
    int n, int koff) {
  constexpr int NC = CI / 64;  // 64-wide K chunks per offset
  __shared__ unsigned short Alds[128 * 64];
  __shared__ unsigned short Blds[128 * 64];

  const int tid = threadIdx.x;
  const int lane = tid & 63;
  const int wave = tid >> 6;
  const int row0 = blockIdx.x * 128;
  const int wrow = (wave >> 1) * 64;
  const int wcol = (wave & 1) * 64;
  const int m = lane & 15;
  const int q = lane >> 4;
  const int rbase = tid >> 3;  // staging row 0..31 (4 rows: +32c)
  const int seg = tid & 7;     // 8-channel segment within row

  frag_cd acc[4][4];
#pragma unroll
  for (int i = 0; i < 4; ++i)
#pragma unroll
    for (int j = 0; j < 4; ++j) acc[i][j] = (frag_cd){0.f, 0.f, 0.f, 0.f};

  int idx_cur[4], idx_nxt[4];
  uint4 aval[4], bval[4];
  uint4 aval2[4];  // second half of fp32 rows (XF32 only)

  auto load_idx = [&](int ko, int (&dst)[4]) {
#pragma unroll
    for (int c = 0; c < 4; ++c) {
      const int grow = row0 + rbase + 32 * c;
      int v = -1;
      if (grow < n) v = GATHER ? nbr[(size_t)ko * n + grow] : grow;
      dst[c] = v;
    }
  };
  auto prefetch = [&](const int (&idx)[4], int ko, int kc) {
#pragma unroll
    for (int c = 0; c < 4; ++c) {
      if (XF32) {
        uint4 lo = make_uint4(0u, 0u, 0u, 0u), hi = lo;
        if (idx[c] >= 0) {
          const float* xp = (const float*)Xv + (size_t)idx[c] * CI + kc * 64 + seg * 8;
          lo = *(const uint4*)xp;
          hi = *(const uint4*)(xp + 4);
        }
        aval[c] = lo; aval2[c] = hi;
      } else {
        uint4 v = make_uint4(0u, 0u, 0u, 0u);
        if (idx[c] >= 0)
          v = *(const uint4*)((const unsigned short*)Xv + (size_t)idx[c] * CI + kc * 64 + seg * 8);
        aval[c] = v;
      }
      bval[c] = *(const uint4*)(Wt + (size_t)ko * (128 * CI) +
                                (size_t)(rbase + 32 * c) * CI + kc * 64 + seg * 8);
    }
  };
  auto store_lds = [&]() {
    const int sseg = (seg ^ (rbase & 7)) * 8;  // XOR swizzle
#pragma unroll
    for (int c = 0; c < 4; ++c) {
      uint4 a = XF32 ? pack_bf16(aval[c], aval2[c]) : aval[c];
      *(uint4*)(Alds + (rbase + 32 * c) * 64 + sseg) = a;
      *(uint4*)(Blds + (rbase + 32 * c) * 64 + sseg) = bval[c];
    }
  };
  auto do_mfma = [&]() {
#pragma unroll
    for (int kk = 0; kk < 64; kk += 32) {
      frag_ab a[4], b[4];
      const int sb = kk / 8 + q;              // source segment 0..7
      const int mseg = (sb ^ (m & 7)) * 8;    // row&7 == m&7 for frag rows
#pragma unroll
      for (int i = 0; i < 4; ++i)
        a[i] = *(const frag_ab*)(Alds + (wrow + 16 * i + m) * 64 + mseg);
#pragma unroll
      for (int j = 0; j < 4; ++j)
        b[j] = *(const frag_ab*)(Blds + (wcol + 16 * j + m) * 64 + mseg);
#pragma unroll
      for (int i = 0; i < 4; ++i)
#pragma unroll
        for (int j = 0; j < 4; ++j)
          acc[i][j] = __builtin_amdgcn_mfma_f32_16x16x32_bf16(a[i], b[j],
                                                              acc[i][j], 0, 0, 0);
    }
  };

  // ---- pipeline prologue ----
  load_idx(0, idx_cur);
  prefetch(idx_cur, 0, 0);
  if (koff > 1) load_idx(1, idx_nxt);

  const int T = koff * NC;
  for (int t = 0; t < T; ++t) {
    __syncthreads();   // previous MFMA done reading LDS
    store_lds();       // waits on prefetched loads (issued one chunk ago)
    __syncthreads();   // LDS visible
    const int t1 = t + 1;
    if (t1 < T) {
      const int ko1 = t1 / NC;
      const int kc1 = t1 - ko1 * NC;
      if (NC == 1 || kc1 == 0) {  // entering a new offset
#pragma unroll
        for (int c = 0; c < 4; ++c) idx_cur[c] = idx_nxt[c];
        prefetch(idx_cur, ko1, 0);
        if (ko1 + 1 < koff) load_idx(ko1 + 1, idx_nxt);
      } else {
        prefetch(idx_cur, ko1, kc1);
      }
    }
    do_mfma();
  }

  // ---- epilogue: C/D layout col=lane&15, row=(lane>>4)*4+reg ----
#pragma unroll
  for (int i = 0; i < 4; ++i) {
#pragma unroll
    for (int r = 0; r < 4; ++r) {
      const int grow = row0 + wrow + 16 * i + q * 4 + r;
      if (grow < n) {
#pragma unroll
        for (int j = 0; j < 4; ++j) {
          const int gcol = wcol + 16 * j + m;
          if (OF32)
            ((float*)Yv)[(size_t)grow * COUT + gcol] = acc[i][j][r];
          else
            ((unsigned short*)Yv)[(size_t)grow * COUT + gcol] = f2bf(acc[i][j][r]);
        }
      }
    }
  }
}

// dst[k][co][ci] (bf16) = src[k][ci][co] (fp32)
__global__ void transpose_w(const float* __restrict__ src,
                            unsigned short* __restrict__ dst, int kk, int ci,
                            int co) {
  int gid = blockIdx.x * blockDim.x + threadIdx.x;
  int total = kk * ci * co;
  if (gid >= total) return;
  int per = ci * co;
  int k = gid / per;
  int rem = gid - k * per;
  int o = rem / ci;
  int i = rem - o * ci;
  dst[gid] = f2bf(src[(size_t)k * per + (size_t)i * co + o]);
}

// per-channel sum / sumsq of [n][COUT] -> sums[0:128]=sum, [128:256]=sumsq
template <bool F32>
__global__ void stats_kernel(const void* __restrict__ xv,
                             float* __restrict__ sums, int n) {
  int t = threadIdx.x;
  int c2 = (t & 63) * 2;
  int row = blockIdx.x * 4 + (t >> 6);
  const int stride = gridDim.x * 4;
  float s0 = 0.f, s1 = 0.f, q0 = 0.f, q1 = 0.f;
  for (; row < n; row += stride) {
    float f0, f1;
    if (F32) {
      const float* x = (const float*)xv + (size_t)row * COUT + c2;
      f0 = x[0]; f1 = x[1];
    } else {
      unsigned int v = *(const unsigned int*)((const unsigned short*)xv + (size_t)row * COUT + c2);
      f0 = bf2f((unsigned short)(v & 0xffffu));
      f1 = bf2f((unsigned short)(v >> 16));
    }
    s0 += f0; q0 += f0 * f0;
    s1 += f1; q1 += f1 * f1;
  }
  atomicAdd(&sums[c2], s0);
  atomicAdd(&sums[c2 + 1], s1);
  atomicAdd(&sums[COUT + c2], q0);
  atomicAdd(&sums[COUT + c2 + 1], q1);
}

__global__ void finalize_kernel(const float* __restrict__ sums,
                                const float* __restrict__ gamma,
                                const float* __restrict__ beta,
                                float* __restrict__ scale,
                                float* __restrict__ shift, int n) {
  int c = threadIdx.x;
  float inv_n = 1.f / (float)n;
  float mean = sums[c] * inv_n;
  float var = sums[COUT + c] * inv_n - mean * mean;
  float sc = gamma[c] * rsqrtf(var + EPS);
  scale[c] = sc;
  shift[c] = beta[c] - mean * sc;
}

// in-place bf16 x = relu(x*scale + shift), 8 bf16 per thread
__global__ void norm_relu_kernel(unsigned short* __restrict__ x,
                                 const float* __restrict__ scale,
                                 const float* __restrict__ shift, int total8) {
  int gid = blockIdx.x * 256 + threadIdx.x;
  if (gid >= total8) return;
  size_t i = (size_t)gid * 8;
  int c0 = (int)(i & 127);
  uint4 v = *(const uint4*)(x + i);
  unsigned int w[4] = {v.x, v.y, v.z, v.w};
  unsigned int wo[4];
#pragma unroll
  for (int e = 0; e < 4; ++e) {
    int c = c0 + 2 * e;
    float f0 = bf2f((unsigned short)(w[e] & 0xffffu));
    float f1 = bf2f((unsigned short)(w[e] >> 16));
    f0 = fmaxf(f0 * scale[c] + shift[c], 0.f);
    f1 = fmaxf(f1 * scale[c + 1] + shift[c + 1], 0.f);
    wo[e] = (unsigned int)f2bf(f0) | ((unsigned int)f2bf(f1) << 16);
  }
  *(uint4*)(x + i) = make_uint4(wo[0], wo[1], wo[2], wo[3]);
}

// out(fp32, in-place on h2) = relu(h2*scale2+shift2 + s*scaled+shiftd)
__global__ void final_kernel(float* __restrict__ h2,
                             const unsigned short* __restrict__ s,
                             const float* __restrict__ scale2,
                             const float* __restrict__ shift2,
                             const float* __restrict__ scaled,
                             const float* __restrict__ shiftd, int total4) {
  int gid = blockIdx.x * 256 + threadIdx.x;
  if (gid >= total4) return;
  size_t i = (size_t)gid * 4;
  int c = (int)(i & 127);
  float4 a = *(const float4*)(h2 + i);
  uint2 sv = *(const uint2*)(s + i);
  float b0 = bf2f((unsigned short)(sv.x & 0xffffu));
  float b1 = bf2f((unsigned short)(sv.x >> 16));
  float b2 = bf2f((unsigned short)(sv.y & 0xffffu));
  float b3 = bf2f((unsigned short)(sv.y >> 16));
  float4 o;
  o.x = fmaxf(a.x * scale2[c] + shift2[c] + b0 * scaled[c] + shiftd[c], 0.f);
  o.y = fmaxf(a.y * scale2[c + 1] + shift2[c + 1] + b1 * scaled[c + 1] + shiftd[c + 1], 0.f);
  o.z = fmaxf(a.z * scale2[c + 2] + shift2[c + 2] + b2 * scaled[c + 2] + shiftd[c + 2], 0.f);
  o.w = fmaxf(a.w * scale2[c + 3] + shift2[c + 3] + b3 * scaled[c + 3] + shiftd[c + 3], 0.f);
  *(float4*)(h2 + i) = o;
}

extern "C" void kernel_launch(void* const* d_in, const int* in_sizes, int n_in,
                              void* d_out, int out_size, void* d_ws,
                              size_t ws_size, hipStream_t stream) {
  (void)n_in; (void)out_size; (void)ws_size;
  const float* feats = (const float*)d_in[0];
  const int* nbr1 = (const int*)d_in[1];
  const int* nbr2 = (const int*)d_in[2];
  const float* W1 = (const float*)d_in[3];
  const float* W2 = (const float*)d_in[4];
  const float* Wd = (const float*)d_in[5];
  const float* g1 = (const float*)d_in[6];
  const float* b1 = (const float*)d_in[7];
  const float* g2 = (const float*)d_in[8];
  const float* b2 = (const float*)d_in[9];
  const float* gd = (const float*)d_in[10];
  const float* bd = (const float*)d_in[11];

  const int n = in_sizes[0] / CIN;  // 200000

  // ws layout identical to round 2 (known-good <= 103.75 MB)
  char* ws = (char*)d_ws;
  unsigned short* Wt1 = (unsigned short*)(ws);
  unsigned short* Wt2 = (unsigned short*)(ws + 442368);
  unsigned short* Wdt = (unsigned short*)(ws + 1327104);
  unsigned short* h1 = (unsigned short*)(ws + 1343488);
  unsigned short* sX = (unsigned short*)(ws + 52543488);
  float* sums1 = (float*)(ws + 103743488);
  float* sums2 = sums1 + 2 * COUT;
  float* sumsd = sums1 + 4 * COUT;
  float* scale1 = sums1 + 6 * COUT;
  float* shift1 = scale1 + COUT;
  float* scale2 = scale1 + 2 * COUT;
  float* shift2 = scale1 + 3 * COUT;
  float* scaled = scale1 + 4 * COUT;
  float* shiftd = scale1 + 5 * COUT;

  float* h2 = (float*)d_out;  // conv2 output lives in d_out (fp32)

  hipMemsetAsync(sums1, 0, 6 * COUT * sizeof(float), stream);

  transpose_w<<<(KOFF * CIN * COUT + 255) / 256, 256, 0, stream>>>(W1, Wt1, KOFF, CIN, COUT);
  transpose_w<<<(KOFF * COUT * COUT + 255) / 256, 256, 0, stream>>>(W2, Wt2, KOFF, COUT, COUT);
  transpose_w<<<(CIN * COUT + 255) / 256, 256, 0, stream>>>(Wd, Wdt, 1, CIN, COUT);

  const int mblocks = (n + 127) / 128;
  conv_kernel<CIN, true, true, false><<<mblocks, 256, 0, stream>>>(feats, nbr1, Wt1, h1, n, KOFF);
  conv_kernel<CIN, false, true, false><<<mblocks, 256, 0, stream>>>(feats, nullptr, Wdt, sX, n, 1);

  stats_kernel<false><<<512, 256, 0, stream>>>(h1, sums1, n);
  finalize_kernel<<<1, COUT, 0, stream>>>(sums1, g1, b1, scale1, shift1, n);

  const int total8 = n * COUT / 8;
  norm_relu_kernel<<<(total8 + 255) / 256, 256, 0, stream>>>(h1, scale1, shift1, total8);

  conv_kernel<COUT, true, false, true><<<mblocks, 256, 0, stream>>>(h1, nbr2, Wt2, h2, n, KOFF);

  stats_kernel<true><<<512, 256, 0, stream>>>(h2, sums2, n);
  stats_kernel<false><<<512, 256, 0, stream>>>(sX, sumsd, n);
  finalize_kernel<<<1, COUT, 0, stream>>>(sums2, g2, b2, scale2, shift2, n);
  finalize_kernel<<<1, COUT, 0, stream>>>(sumsd, gd, bd, scaled, shiftd, n);

  const int total4 = n * COUT / 4;
  final_kernel<<<(total4 + 255) / 256, 256, 0, stream>>>(h2, sX, scale2, shift2, scaled, shiftd, total4);
}

// Round 4
// 983.925 us; speedup vs baseline: 1.6497x; 1.6497x over previous
//
#include <hip/hip_runtime.h>
#include <stdint.h>

#define KOFF 27
#define CIN 64
#define COUT 128
#define EPS 1e-5f

using frag_ab = __attribute__((ext_vector_type(8))) short;
using frag_cd = __attribute__((ext_vector_type(4))) float;

__device__ __forceinline__ float bf2f(unsigned short u) {
  union { unsigned int i; float f; } x; x.i = ((unsigned int)u) << 16; return x.f;
}
__device__ __forceinline__ unsigned short f2bf(float f) {
  union { float f; unsigned int i; } x; x.f = f;
  unsigned int u = x.i;
  u += 0x7fffu + ((u >> 16) & 1u);   // round-to-nearest-even
  return (unsigned short)(u >> 16);
}

// async global->LDS, 16 B per lane; LDS dest = wave-uniform base + lane*16
__device__ __forceinline__ void gld16(const void* gptr, void* lptr) {
  __builtin_amdgcn_global_load_lds(
      (const __attribute__((address_space(1))) unsigned int*)gptr,
      (__attribute__((address_space(3))) unsigned int*)lptr, 16, 0, 0);
}

// ---------------------------------------------------------------------------
// Gather-GEMM via global_load_lds: Y[row] = sum_k X[nbr[k][row]] @ W[k].
// X bf16 [n][CI]; Wt bf16 [k][co][ci]; Y bf16 or fp32 (OF32).
// BLOCK 128x128, 256 thr = 4 waves (2x2 of 64x64/wave). BK=32 chunks,
// double-buffered LDS (2 * (8+8) KB = 32 KB), staged entirely by
// global_load_lds (no VGPR round-trip -> no spills). Raw s_barrier +
// manual vmcnt(0) so next-chunk loads overlap current-chunk MFMA.
// Masked rows (idx<0) load from a 256 B zero page.
// LDS A/B layout per buffer: [128 rows][32 ch] packed, 64 B rows; lane
// fetches global seg g = (lane&3) ^ ((row>>1)&3) -> 2-way ds_read_b128.
// ---------------------------------------------------------------------------
template <int CI, bool GATHER, bool OF32>
__global__ __launch_bounds__(256, 3) void conv_kernel(
    const unsigned short* __restrict__ X, const int* __restrict__ nbr,
    const unsigned short* __restrict__ Wt, void* __restrict__ Yv,
    const unsigned short* __restrict__ zpage, int n, int koff) {
  constexpr int NC = CI / 32;  // chunks per offset
  __shared__ unsigned short Alds[2][128 * 32];
  __shared__ unsigned short Blds[2][128 * 32];

  const int tid = threadIdx.x;
  const int lane = tid & 63;
  const int wave = tid >> 6;
  const int row0 = blockIdx.x * 128;
  const int wrow = (wave >> 1) * 64;
  const int wcol = (wave & 1) * 64;
  const int m = lane & 15;
  const int q = lane >> 4;
  // staging geometry: instr i in {0,1}; rows = i*64 + wave*16 + (lane>>2)
  const int srow0 = wave * 16 + (lane >> 2);
  const int sl = lane & 3;

  frag_cd acc[4][4];
#pragma unroll
  for (int i = 0; i < 4; ++i)
#pragma unroll
    for (int j = 0; j < 4; ++j) acc[i][j] = (frag_cd){0.f, 0.f, 0.f, 0.f};

  int idxc[2], idxn[2];
  auto load_idx = [&](int ko, int (&dst)[2]) {
#pragma unroll
    for (int i = 0; i < 2; ++i) {
      const int grow = row0 + srow0 + i * 64;
      int v = -1;
      if (grow < n) v = GATHER ? nbr[(size_t)ko * n + grow] : grow;
      dst[i] = v;
    }
  };
  auto stage = [&](int buf, int ko, int kc, const int (&idx)[2]) {
#pragma unroll
    for (int i = 0; i < 2; ++i) {
      const int row = srow0 + i * 64;
      const int g = sl ^ ((row >> 1) & 3);
      const unsigned short* ga =
          (idx[i] >= 0) ? X + (size_t)idx[i] * CI + kc * 32 + g * 8 : zpage;
      gld16(ga, &Alds[buf][(i * 64 + wave * 16) * 32]);
      const unsigned short* gb =
          Wt + (size_t)ko * (128 * CI) + (size_t)row * CI + kc * 32 + g * 8;
      gld16(gb, &Blds[buf][(i * 64 + wave * 16) * 32]);
    }
  };
  auto do_mfma = [&](int buf) {
    frag_ab a[4], b[4];
#pragma unroll
    for (int i = 0; i < 4; ++i) {
      const int row = wrow + 16 * i + m;
      a[i] = *(const frag_ab*)(&Alds[buf][row * 32 + (q ^ ((row >> 1) & 3)) * 8]);
    }
#pragma unroll
    for (int j = 0; j < 4; ++j) {
      const int row = wcol + 16 * j + m;
      b[j] = *(const frag_ab*)(&Blds[buf][row * 32 + (q ^ ((row >> 1) & 3)) * 8]);
    }
#pragma unroll
    for (int i = 0; i < 4; ++i)
#pragma unroll
      for (int j = 0; j < 4; ++j)
        acc[i][j] = __builtin_amdgcn_mfma_f32_16x16x32_bf16(a[i], b[j],
                                                            acc[i][j], 0, 0, 0);
  };

  const int T = koff * NC;
  load_idx(0, idxc);
  if (koff > 1) load_idx(1, idxn);
  stage(0, 0, 0, idxc);
  asm volatile("s_waitcnt vmcnt(0)" ::: "memory");
  __builtin_amdgcn_s_barrier();

  for (int t = 0; t < T; ++t) {
    const int s = t + 1;
    if (s < T) {
      const int kos = s / NC;
      const int kcs = s - kos * NC;
      if (kcs == 0) {  // staging enters a new offset
        idxc[0] = idxn[0];
        idxc[1] = idxn[1];
        if (kos + 1 < koff) load_idx(kos + 1, idxn);
      }
      stage(s & 1, kos, kcs, idxc);
    }
    do_mfma(t & 1);
    asm volatile("s_waitcnt vmcnt(0)" ::: "memory");
    __builtin_amdgcn_s_barrier();
  }

  // epilogue: C/D layout col=lane&15, row=(lane>>4)*4+reg
#pragma unroll
  for (int i = 0; i < 4; ++i) {
#pragma unroll
    for (int r = 0; r < 4; ++r) {
      const int grow = row0 + wrow + 16 * i + q * 4 + r;
      if (grow < n) {
#pragma unroll
        for (int j = 0; j < 4; ++j) {
          const int gcol = wcol + 16 * j + m;
          if (OF32)
            ((float*)Yv)[(size_t)grow * COUT + gcol] = acc[i][j][r];
          else
            ((unsigned short*)Yv)[(size_t)grow * COUT + gcol] = f2bf(acc[i][j][r]);
        }
      }
    }
  }
}

// fp32 -> bf16, 8 per thread
__global__ void convert_kernel(const float* __restrict__ src,
                               unsigned short* __restrict__ dst, int total8) {
  int gid = blockIdx.x * 256 + threadIdx.x;
  if (gid >= total8) return;
  const float* s = src + (size_t)gid * 8;
  float4 lo = *(const float4*)s;
  float4 hi = *(const float4*)(s + 4);
  uint4 r;
  r.x = (unsigned)f2bf(lo.x) | ((unsigned)f2bf(lo.y) << 16);
  r.y = (unsigned)f2bf(lo.z) | ((unsigned)f2bf(lo.w) << 16);
  r.z = (unsigned)f2bf(hi.x) | ((unsigned)f2bf(hi.y) << 16);
  r.w = (unsigned)f2bf(hi.z) | ((unsigned)f2bf(hi.w) << 16);
  *(uint4*)(dst + (size_t)gid * 8) = r;
}

// dst[k][co][ci] (bf16) = src[k][ci][co] (fp32)
__global__ void transpose_w(const float* __restrict__ src,
                            unsigned short* __restrict__ dst, int kk, int ci,
                            int co) {
  int gid = blockIdx.x * blockDim.x + threadIdx.x;
  int total = kk * ci * co;
  if (gid >= total) return;
  int per = ci * co;
  int k = gid / per;
  int rem = gid - k * per;
  int o = rem / ci;
  int i = rem - o * ci;
  dst[gid] = f2bf(src[(size_t)k * per + (size_t)i * co + o]);
}

// per-channel sum / sumsq of [n][COUT] -> sums[0:128]=sum, [128:256]=sumsq
template <bool F32>
__global__ void stats_kernel(const void* __restrict__ xv,
                             float* __restrict__ sums, int n) {
  int t = threadIdx.x;
  int c2 = (t & 63) * 2;
  int row = blockIdx.x * 4 + (t >> 6);
  const int stride = gridDim.x * 4;
  float s0 = 0.f, s1 = 0.f, q0 = 0.f, q1 = 0.f;
  for (; row < n; row += stride) {
    float f0, f1;
    if (F32) {
      const float* x = (const float*)xv + (size_t)row * COUT + c2;
      f0 = x[0]; f1 = x[1];
    } else {
      unsigned int v = *(const unsigned int*)((const unsigned short*)xv + (size_t)row * COUT + c2);
      f0 = bf2f((unsigned short)(v & 0xffffu));
      f1 = bf2f((unsigned short)(v >> 16));
    }
    s0 += f0; q0 += f0 * f0;
    s1 += f1; q1 += f1 * f1;
  }
  atomicAdd(&sums[c2], s0);
  atomicAdd(&sums[c2 + 1], s1);
  atomicAdd(&sums[COUT + c2], q0);
  atomicAdd(&sums[COUT + c2 + 1], q1);
}

__global__ void finalize_kernel(const float* __restrict__ sums,
                                const float* __restrict__ gamma,
                                const float* __restrict__ beta,
                                float* __restrict__ scale,
                                float* __restrict__ shift, int n) {
  int c = threadIdx.x;
  float inv_n = 1.f / (float)n;
  float mean = sums[c] * inv_n;
  float var = sums[COUT + c] * inv_n - mean * mean;
  float sc = gamma[c] * rsqrtf(var + EPS);
  scale[c] = sc;
  shift[c] = beta[c] - mean * sc;
}

// in-place bf16 x = relu(x*scale + shift), 8 bf16 per thread
__global__ void norm_relu_kernel(unsigned short* __restrict__ x,
                                 const float* __restrict__ scale,
                                 const float* __restrict__ shift, int total8) {
  int gid = blockIdx.x * 256 + threadIdx.x;
  if (gid >= total8) return;
  size_t i = (size_t)gid * 8;
  int c0 = (int)(i & 127);
  uint4 v = *(const uint4*)(x + i);
  unsigned int w[4] = {v.x, v.y, v.z, v.w};
  unsigned int wo[4];
#pragma unroll
  for (int e = 0; e < 4; ++e) {
    int c = c0 + 2 * e;
    float f0 = bf2f((unsigned short)(w[e] & 0xffffu));
    float f1 = bf2f((unsigned short)(w[e] >> 16));
    f0 = fmaxf(f0 * scale[c] + shift[c], 0.f);
    f1 = fmaxf(f1 * scale[c + 1] + shift[c + 1], 0.f);
    wo[e] = (unsigned int)f2bf(f0) | ((unsigned int)f2bf(f1) << 16);
  }
  *(uint4*)(x + i) = make_uint4(wo[0], wo[1], wo[2], wo[3]);
}

// out(fp32, in-place on h2) = relu(h2*scale2+shift2 + s*scaled+shiftd)
__global__ void final_kernel(float* __restrict__ h2,
                             const unsigned short* __restrict__ s,
                             const float* __restrict__ scale2,
                             const float* __restrict__ shift2,
                             const float* __restrict__ scaled,
                             const float* __restrict__ shiftd, int total4) {
  int gid = blockIdx.x * 256 + threadIdx.x;
  if (gid >= total4) return;
  size_t i = (size_t)gid * 4;
  int c = (int)(i & 127);
  float4 a = *(const float4*)(h2 + i);
  uint2 sv = *(const uint2*)(s + i);
  float b0 = bf2f((unsigned short)(sv.x & 0xffffu));
  float b1 = bf2f((unsigned short)(sv.x >> 16));
  float b2 = bf2f((unsigned short)(sv.y & 0xffffu));
  float b3 = bf2f((unsigned short)(sv.y >> 16));
  float4 o;
  o.x = fmaxf(a.x * scale2[c] + shift2[c] + b0 * scaled[c] + shiftd[c], 0.f);
  o.y = fmaxf(a.y * scale2[c + 1] + shift2[c + 1] + b1 * scaled[c + 1] + shiftd[c + 1], 0.f);
  o.z = fmaxf(a.z * scale2[c + 2] + shift2[c + 2] + b2 * scaled[c + 2] + shiftd[c + 2], 0.f);
  o.w = fmaxf(a.w * scale2[c + 3] + shift2[c + 3] + b3 * scaled[c + 3] + shiftd[c + 3], 0.f);
  *(float4*)(h2 + i) = o;
}

extern "C" void kernel_launch(void* const* d_in, const int* in_sizes, int n_in,
                              void* d_out, int out_size, void* d_ws,
                              size_t ws_size, hipStream_t stream) {
  (void)n_in; (void)out_size; (void)ws_size;
  const float* feats = (const float*)d_in[0];
  const int* nbr1 = (const int*)d_in[1];
  const int* nbr2 = (const int*)d_in[2];
  const float* W1 = (const float*)d_in[3];
  const float* W2 = (const float*)d_in[4];
  const float* Wd = (const float*)d_in[5];
  const float* g1 = (const float*)d_in[6];
  const float* b1 = (const float*)d_in[7];
  const float* g2 = (const float*)d_in[8];
  const float* b2 = (const float*)d_in[9];
  const float* gd = (const float*)d_in[10];
  const float* bd = (const float*)d_in[11];

  const int n = in_sizes[0] / CIN;  // 200000

  // ws layout (known-good footprint + 8.5 KB tail):
  //   Wt1[442368] Wt2[884736] Wdt[16384] h1_bf16[51.2e6] sX_bf16[51.2e6]
  //   stats/scales [6144] pad zpage[256]
  char* ws = (char*)d_ws;
  unsigned short* Wt1 = (unsigned short*)(ws);
  unsigned short* Wt2 = (unsigned short*)(ws + 442368);
  unsigned short* Wdt = (unsigned short*)(ws + 1327104);
  unsigned short* h1 = (unsigned short*)(ws + 1343488);
  unsigned short* sX = (unsigned short*)(ws + 52543488);
  float* sums1 = (float*)(ws + 103743488);
  float* sums2 = sums1 + 2 * COUT;
  float* sumsd = sums1 + 4 * COUT;
  float* scale1 = sums1 + 6 * COUT;
  float* shift1 = scale1 + COUT;
  float* scale2 = scale1 + 2 * COUT;
  float* shift2 = scale1 + 3 * COUT;
  float* scaled = scale1 + 4 * COUT;
  float* shiftd = scale1 + 5 * COUT;
  unsigned short* zpage = (unsigned short*)(ws + 103743488 + 8192);

  float* h2 = (float*)d_out;  // conv2 output -> d_out (fp32)
  // bf16 feats stash: last 25.6 MB of d_out; conv2 clobbers it afterwards
  unsigned short* featsb = (unsigned short*)((char*)d_out + 76800000);

  // zero sums + scales + zero page in one shot
  hipMemsetAsync(sums1, 0, 8192 + 256, stream);

  transpose_w<<<(KOFF * CIN * COUT + 255) / 256, 256, 0, stream>>>(W1, Wt1, KOFF, CIN, COUT);
  transpose_w<<<(KOFF * COUT * COUT + 255) / 256, 256, 0, stream>>>(W2, Wt2, KOFF, COUT, COUT);
  transpose_w<<<(CIN * COUT + 255) / 256, 256, 0, stream>>>(Wd, Wdt, 1, CIN, COUT);

  const int f8 = n * CIN / 8;
  convert_kernel<<<(f8 + 255) / 256, 256, 0, stream>>>(feats, featsb, f8);

  const int mblocks = (n + 127) / 128;
  conv_kernel<CIN, true, false><<<mblocks, 256, 0, stream>>>(featsb, nbr1, Wt1, h1, zpage, n, KOFF);
  conv_kernel<CIN, false, false><<<mblocks, 256, 0, stream>>>(featsb, nullptr, Wdt, sX, zpage, n, 1);

  stats_kernel<false><<<512, 256, 0, stream>>>(h1, sums1, n);
  finalize_kernel<<<1, COUT, 0, stream>>>(sums1, g1, b1, scale1, shift1, n);

  const int total8 = n * COUT / 8;
  norm_relu_kernel<<<(total8 + 255) / 256, 256, 0, stream>>>(h1, scale1, shift1, total8);

  conv_kernel<COUT, true, true><<<mblocks, 256, 0, stream>>>(h1, nbr2, Wt2, h2, zpage, n, KOFF);

  stats_kernel<true><<<512, 256, 0, stream>>>(h2, sums2, n);
  stats_kernel<false><<<512, 256, 0, stream>>>(sX, sumsd, n);
  finalize_kernel<<<1, COUT, 0, stream>>>(sums2, g2, b2, scale2, shift2, n);
  finalize_kernel<<<1, COUT, 0, stream>>>(sumsd, gd, bd, scaled, shiftd, n);

  const int total4 = n * COUT / 4;
  final_kernel<<<(total4 + 255) / 256, 256, 0, stream>>>(h2, sX, scale2, shift2, scaled, shiftd, total4);
}

// Round 5
// 794.333 us; speedup vs baseline: 2.0435x; 1.2387x over previous
//
#include <hip/hip_runtime.h>
#include <stdint.h>

#define KOFF 27
#define CIN 64
#define COUT 128
#define EPS 1e-5f

using frag_ab = __attribute__((ext_vector_type(8))) short;
using frag_cd = __attribute__((ext_vector_type(4))) float;

__device__ __forceinline__ float bf2f(unsigned short u) {
  union { unsigned int i; float f; } x; x.i = ((unsigned int)u) << 16; return x.f;
}
__device__ __forceinline__ unsigned short f2bf(float f) {
  union { float f; unsigned int i; } x; x.f = f;
  unsigned int u = x.i;
  u += 0x7fffu + ((u >> 16) & 1u);   // round-to-nearest-even
  return (unsigned short)(u >> 16);
}

// async global->LDS, 16 B per lane; LDS dest = wave-uniform base + lane*16
__device__ __forceinline__ void gld16(const void* gptr, void* lptr) {
  __builtin_amdgcn_global_load_lds(
      (const __attribute__((address_space(1))) unsigned int*)gptr,
      (__attribute__((address_space(3))) unsigned int*)lptr, 16, 0, 0);
}

// ---------------------------------------------------------------------------
// Gather-GEMM via global_load_lds: Y[row] = sum_k X[nbr[k][row]] @ W[k].
// X bf16 [n][CI]; Wt bf16 [k][co][ci]; Y bf16 or fp32 (OF32).
// BLOCK 128x128, 256 thr = 4 waves (2x2 of 64x64/wave). BK=32 chunks,
// TRIPLE-buffered LDS (3 * 16 KB = 48 KB). Pipeline: stage(t+2) issued at
// iter t; per-iter wait is vmcnt(4) (drains stage(t), keeps stage(t+1) in
// flight) -> gather latency hidden by 2 MFMA batches x 3 resident blocks.
// idx loads issued before stage() each iteration so the newest-4 in-flight
// loads at any wait are exactly the most recent stage.
// Masked rows (idx<0) load a 256 B zero page -> acc contribution 0, which
// also makes fused BN-stats correct without masking.
// Fused stats: per-block per-channel sum/sumsq of fp32 acc -> atomicAdd.
// ---------------------------------------------------------------------------
template <int CI, bool GATHER, bool OF32>
__global__ __launch_bounds__(256, 3) void conv_kernel(
    const unsigned short* __restrict__ X, const int* __restrict__ nbr,
    const unsigned short* __restrict__ Wt, void* __restrict__ Yv,
    const unsigned short* __restrict__ zpage, float* __restrict__ sums,
    int n, int koff) {
  constexpr int NC = CI / 32;  // chunks per offset (2 or 4)
  __shared__ unsigned short Alds[3][128 * 32];
  __shared__ unsigned short Blds[3][128 * 32];

  const int tid = threadIdx.x;
  const int lane = tid & 63;
  const int wave = tid >> 6;
  const int row0 = blockIdx.x * 128;
  const int wrow = (wave >> 1) * 64;
  const int wcol = (wave & 1) * 64;
  const int m = lane & 15;
  const int q = lane >> 4;
  const int srow0 = wave * 16 + (lane >> 2);
  const int sl = lane & 3;

  frag_cd acc[4][4];
#pragma unroll
  for (int i = 0; i < 4; ++i)
#pragma unroll
    for (int j = 0; j < 4; ++j) acc[i][j] = (frag_cd){0.f, 0.f, 0.f, 0.f};

  int idxc[2], idxn[2];
  auto load_idx = [&](int ko, int (&dst)[2]) {
#pragma unroll
    for (int i = 0; i < 2; ++i) {
      const int grow = row0 + srow0 + i * 64;
      int v = -1;
      if (grow < n) v = GATHER ? nbr[(size_t)ko * n + grow] : grow;
      dst[i] = v;
    }
  };
  auto stage = [&](int buf, int ko, int kc, const int (&idx)[2]) {
#pragma unroll
    for (int i = 0; i < 2; ++i) {
      const int row = srow0 + i * 64;
      const int g = sl ^ ((row >> 1) & 3);
      const unsigned short* ga =
          (idx[i] >= 0) ? X + (size_t)idx[i] * CI + kc * 32 + g * 8 : zpage;
      gld16(ga, &Alds[buf][(i * 64 + wave * 16) * 32]);
      const unsigned short* gb =
          Wt + (size_t)ko * (128 * CI) + (size_t)row * CI + kc * 32 + g * 8;
      gld16(gb, &Blds[buf][(i * 64 + wave * 16) * 32]);
    }
  };
  auto do_mfma = [&](int buf) {
    frag_ab a[4], b[4];
#pragma unroll
    for (int i = 0; i < 4; ++i) {
      const int row = wrow + 16 * i + m;
      a[i] = *(const frag_ab*)(&Alds[buf][row * 32 + (q ^ ((row >> 1) & 3)) * 8]);
    }
#pragma unroll
    for (int j = 0; j < 4; ++j) {
      const int row = wcol + 16 * j + m;
      b[j] = *(const frag_ab*)(&Blds[buf][row * 32 + (q ^ ((row >> 1) & 3)) * 8]);
    }
#pragma unroll
    for (int i = 0; i < 4; ++i)
#pragma unroll
      for (int j = 0; j < 4; ++j)
        acc[i][j] = __builtin_amdgcn_mfma_f32_16x16x32_bf16(a[i], b[j],
                                                            acc[i][j], 0, 0, 0);
  };

  const int T = koff * NC;  // >= 2 always
  load_idx(0, idxc);
  stage(0, 0, 0, idxc);
  stage(1, 0, 1, idxc);  // NC>=2 so chunk 1 is (ko=0, kc=1)
  if (koff > 1) load_idx(1, idxn);

  int bufc = 0;  // t % 3
  for (int t = 0; t < T - 1; ++t) {
    asm volatile("s_waitcnt vmcnt(4)" ::: "memory");
    __builtin_amdgcn_s_barrier();
    const int s = t + 2;
    if (s < T) {
      const int kos = s / NC;        // NC is 2 or 4 -> shift
      const int kcs = s & (NC - 1);
      if (kcs == 0) {  // staging enters a new offset
        idxc[0] = idxn[0];
        idxc[1] = idxn[1];
        if (kos + 1 < koff) load_idx(kos + 1, idxn);
      }
      int bufs = bufc + 2; if (bufs >= 3) bufs -= 3;
      stage(bufs, kos, kcs, idxc);
    }
    do_mfma(bufc);
    if (++bufc == 3) bufc = 0;
  }
  asm volatile("s_waitcnt vmcnt(0)" ::: "memory");
  __builtin_amdgcn_s_barrier();
  do_mfma(bufc);

  // ---- fused BN stats: per-channel sum/sumsq of fp32 acc over block rows --
#pragma unroll
  for (int j = 0; j < 4; ++j) {
    float s = 0.f, qq = 0.f;
#pragma unroll
    for (int i = 0; i < 4; ++i)
#pragma unroll
      for (int r = 0; r < 4; ++r) {
        float v = acc[i][j][r];
        s += v; qq += v * v;
      }
    s += __shfl_xor(s, 16); s += __shfl_xor(s, 32);
    qq += __shfl_xor(qq, 16); qq += __shfl_xor(qq, 32);
    if (lane < 16) {
      const int col = wcol + 16 * j + lane;
      atomicAdd(&sums[col], s);
      atomicAdd(&sums[COUT + col], qq);
    }
  }

  // ---- epilogue: C/D layout col=lane&15, row=(lane>>4)*4+reg ----
#pragma unroll
  for (int i = 0; i < 4; ++i) {
#pragma unroll
    for (int r = 0; r < 4; ++r) {
      const int grow = row0 + wrow + 16 * i + q * 4 + r;
      if (grow < n) {
#pragma unroll
        for (int j = 0; j < 4; ++j) {
          const int gcol = wcol + 16 * j + m;
          if (OF32)
            ((float*)Yv)[(size_t)grow * COUT + gcol] = acc[i][j][r];
          else
            ((unsigned short*)Yv)[(size_t)grow * COUT + gcol] = f2bf(acc[i][j][r]);
        }
      }
    }
  }
}

// fp32 -> bf16, 8 per thread
__global__ void convert_kernel(const float* __restrict__ src,
                               unsigned short* __restrict__ dst, int total8) {
  int gid = blockIdx.x * 256 + threadIdx.x;
  if (gid >= total8) return;
  const float* s = src + (size_t)gid * 8;
  float4 lo = *(const float4*)s;
  float4 hi = *(const float4*)(s + 4);
  uint4 r;
  r.x = (unsigned)f2bf(lo.x) | ((unsigned)f2bf(lo.y) << 16);
  r.y = (unsigned)f2bf(lo.z) | ((unsigned)f2bf(lo.w) << 16);
  r.z = (unsigned)f2bf(hi.x) | ((unsigned)f2bf(hi.y) << 16);
  r.w = (unsigned)f2bf(hi.z) | ((unsigned)f2bf(hi.w) << 16);
  *(uint4*)(dst + (size_t)gid * 8) = r;
}

// dst[k][co][ci] (bf16) = src[k][ci][co] (fp32)
__global__ void transpose_w(const float* __restrict__ src,
                            unsigned short* __restrict__ dst, int kk, int ci,
                            int co) {
  int gid = blockIdx.x * blockDim.x + threadIdx.x;
  int total = kk * ci * co;
  if (gid >= total) return;
  int per = ci * co;
  int k = gid / per;
  int rem = gid - k * per;
  int o = rem / ci;
  int i = rem - o * ci;
  dst[gid] = f2bf(src[(size_t)k * per + (size_t)i * co + o]);
}

__global__ void finalize_kernel(const float* __restrict__ sums,
                                const float* __restrict__ gamma,
                                const float* __restrict__ beta,
                                float* __restrict__ scale,
                                float* __restrict__ shift, int n) {
  int c = threadIdx.x;
  float inv_n = 1.f / (float)n;
  float mean = sums[c] * inv_n;
  float var = sums[COUT + c] * inv_n - mean * mean;
  float sc = gamma[c] * rsqrtf(var + EPS);
  scale[c] = sc;
  shift[c] = beta[c] - mean * sc;
}

// in-place bf16 x = relu(x*scale + shift), 8 bf16 per thread
__global__ void norm_relu_kernel(unsigned short* __restrict__ x,
                                 const float* __restrict__ scale,
                                 const float* __restrict__ shift, int total8) {
  int gid = blockIdx.x * 256 + threadIdx.x;
  if (gid >= total8) return;
  size_t i = (size_t)gid * 8;
  int c0 = (int)(i & 127);
  uint4 v = *(const uint4*)(x + i);
  unsigned int w[4] = {v.x, v.y, v.z, v.w};
  unsigned int wo[4];
#pragma unroll
  for (int e = 0; e < 4; ++e) {
    int c = c0 + 2 * e;
    float f0 = bf2f((unsigned short)(w[e] & 0xffffu));
    float f1 = bf2f((unsigned short)(w[e] >> 16));
    f0 = fmaxf(f0 * scale[c] + shift[c], 0.f);
    f1 = fmaxf(f1 * scale[c + 1] + shift[c + 1], 0.f);
    wo[e] = (unsigned int)f2bf(f0) | ((unsigned int)f2bf(f1) << 16);
  }
  *(uint4*)(x + i) = make_uint4(wo[0], wo[1], wo[2], wo[3]);
}

// out(fp32, in-place on h2) = relu(h2*scale2+shift2 + s*scaled+shiftd)
__global__ void final_kernel(float* __restrict__ h2,
                             const unsigned short* __restrict__ s,
                             const float* __restrict__ scale2,
                             const float* __restrict__ shift2,
                             const float* __restrict__ scaled,
                             const float* __restrict__ shiftd, int total4) {
  int gid = blockIdx.x * 256 + threadIdx.x;
  if (gid >= total4) return;
  size_t i = (size_t)gid * 4;
  int c = (int)(i & 127);
  float4 a = *(const float4*)(h2 + i);
  uint2 sv = *(const uint2*)(s + i);
  float b0 = bf2f((unsigned short)(sv.x & 0xffffu));
  float b1 = bf2f((unsigned short)(sv.x >> 16));
  float b2 = bf2f((unsigned short)(sv.y & 0xffffu));
  float b3 = bf2f((unsigned short)(sv.y >> 16));
  float4 o;
  o.x = fmaxf(a.x * scale2[c] + shift2[c] + b0 * scaled[c] + shiftd[c], 0.f);
  o.y = fmaxf(a.y * scale2[c + 1] + shift2[c + 1] + b1 * scaled[c + 1] + shiftd[c + 1], 0.f);
  o.z = fmaxf(a.z * scale2[c + 2] + shift2[c + 2] + b2 * scaled[c + 2] + shiftd[c + 2], 0.f);
  o.w = fmaxf(a.w * scale2[c + 3] + shift2[c + 3] + b3 * scaled[c + 3] + shiftd[c + 3], 0.f);
  *(float4*)(h2 + i) = o;
}

extern "C" void kernel_launch(void* const* d_in, const int* in_sizes, int n_in,
                              void* d_out, int out_size, void* d_ws,
                              size_t ws_size, hipStream_t stream) {
  (void)n_in; (void)out_size; (void)ws_size;
  const float* feats = (const float*)d_in[0];
  const int* nbr1 = (const int*)d_in[1];
  const int* nbr2 = (const int*)d_in[2];
  const float* W1 = (const float*)d_in[3];
  const float* W2 = (const float*)d_in[4];
  const float* Wd = (const float*)d_in[5];
  const float* g1 = (const float*)d_in[6];
  const float* b1 = (const float*)d_in[7];
  const float* g2 = (const float*)d_in[8];
  const float* b2 = (const float*)d_in[9];
  const float* gd = (const float*)d_in[10];
  const float* bd = (const float*)d_in[11];

  const int n = in_sizes[0] / CIN;  // 200000

  // ws layout (known-good footprint):
  //   Wt1[442368] Wt2[884736] Wdt[16384] h1_bf16[51.2e6] sX_bf16[51.2e6]
  //   stats/scales [8 KB] zpage[256]
  char* ws = (char*)d_ws;
  unsigned short* Wt1 = (unsigned short*)(ws);
  unsigned short* Wt2 = (unsigned short*)(ws + 442368);
  unsigned short* Wdt = (unsigned short*)(ws + 1327104);
  unsigned short* h1 = (unsigned short*)(ws + 1343488);
  unsigned short* sX = (unsigned short*)(ws + 52543488);
  float* sums1 = (float*)(ws + 103743488);
  float* sums2 = sums1 + 2 * COUT;
  float* sumsd = sums1 + 4 * COUT;
  float* scale1 = sums1 + 6 * COUT;
  float* shift1 = scale1 + COUT;
  float* scale2 = scale1 + 2 * COUT;
  float* shift2 = scale1 + 3 * COUT;
  float* scaled = scale1 + 4 * COUT;
  float* shiftd = scale1 + 5 * COUT;
  unsigned short* zpage = (unsigned short*)(ws + 103743488 + 8192);

  float* h2 = (float*)d_out;  // conv2 output -> d_out (fp32)
  // bf16 feats stash: last 25.6 MB of d_out; conv2 clobbers it afterwards
  unsigned short* featsb = (unsigned short*)((char*)d_out + 76800000);

  // zero sums + scales + zero page in one shot
  hipMemsetAsync(sums1, 0, 8192 + 256, stream);

  transpose_w<<<(KOFF * CIN * COUT + 255) / 256, 256, 0, stream>>>(W1, Wt1, KOFF, CIN, COUT);
  transpose_w<<<(KOFF * COUT * COUT + 255) / 256, 256, 0, stream>>>(W2, Wt2, KOFF, COUT, COUT);
  transpose_w<<<(CIN * COUT + 255) / 256, 256, 0, stream>>>(Wd, Wdt, 1, CIN, COUT);

  const int f8 = n * CIN / 8;
  convert_kernel<<<(f8 + 255) / 256, 256, 0, stream>>>(feats, featsb, f8);

  const int mblocks = (n + 127) / 128;
  conv_kernel<CIN, true, false><<<mblocks, 256, 0, stream>>>(featsb, nbr1, Wt1, h1, zpage, sums1, n, KOFF);
  conv_kernel<CIN, false, false><<<mblocks, 256, 0, stream>>>(featsb, nullptr, Wdt, sX, zpage, sumsd, n, 1);

  finalize_kernel<<<1, COUT, 0, stream>>>(sums1, g1, b1, scale1, shift1, n);

  const int total8 = n * COUT / 8;
  norm_relu_kernel<<<(total8 + 255) / 256, 256, 0, stream>>>(h1, scale1, shift1, total8);

  conv_kernel<COUT, true, true><<<mblocks, 256, 0, stream>>>(h1, nbr2, Wt2, h2, zpage, sums2, n, KOFF);

  finalize_kernel<<<1, COUT, 0, stream>>>(sums2, g2, b2, scale2, shift2, n);
  finalize_kernel<<<1, COUT, 0, stream>>>(sumsd, gd, bd, scaled, shiftd, n);

  const int total4 = n * COUT / 4;
  final_kernel<<<(total4 + 255) / 256, 256, 0, stream>>>(h2, sX, scale2, shift2, scaled, shiftd, total4);
}

// Round 6
// 695.961 us; speedup vs baseline: 2.3323x; 1.1413x over previous
//
#include <hip/hip_runtime.h>
#include <stdint.h>

#define KOFF 27
#define CIN 64
#define COUT 128
#define EPS 1e-5f

using frag_ab = __attribute__((ext_vector_type(8))) short;
using frag_cd = __attribute__((ext_vector_type(4))) float;

__device__ __forceinline__ float bf2f(unsigned short u) {
  union { unsigned int i; float f; } x; x.i = ((unsigned int)u) << 16; return x.f;
}
__device__ __forceinline__ unsigned short f2bf(float f) {
  union { float f; unsigned int i; } x; x.f = f;
  unsigned int u = x.i;
  u += 0x7fffu + ((u >> 16) & 1u);   // round-to-nearest-even
  return (unsigned short)(u >> 16);
}

// async global->LDS, 16 B per lane; LDS dest = wave-uniform base + lane*16
__device__ __forceinline__ void gld16(const void* gptr, void* lptr) {
  __builtin_amdgcn_global_load_lds(
      (const __attribute__((address_space(1))) unsigned int*)gptr,
      (__attribute__((address_space(3))) unsigned int*)lptr, 16, 0, 0);
}

// ---------------------------------------------------------------------------
// Gather-GEMM: Y[row] = sum_k X[nbr[k][row]] @ W[k].
// A (gathered X rows, the long-latency path): global_load_lds into a
// TRIPLE-buffered 3x8 KB LDS ring (24 KB -> 3 blocks/CU, unlike 48 KB which
// measured 2). B (weights, L2-hot, 884 KB total): per-lane 16-B register
// loads, double-buffered one chunk ahead; Wt layout [ko][kc][q][co][8] makes
// each 16-lane quad's fragment contiguous. Manual s_waitcnt vmcnt(6) per
// iteration: drains A(t), keeps A(t+1/t+2) + B(t+1) in flight; compiler
// inserts exact waits for B-reg use. Loop unrolled x2 (T=koff*NC is even)
// so B reg buffers have no dynamic index. Masked rows (idx<0) read a 256 B
// zero page -> zero acc contribution -> fused BN stats stay correct.
// ---------------------------------------------------------------------------
template <int CI, bool GATHER, bool OF32>
__global__ __launch_bounds__(256, 3) void conv_kernel(
    const unsigned short* __restrict__ X, const int* __restrict__ nbr,
    const unsigned short* __restrict__ Wt, void* __restrict__ Yv,
    const unsigned short* __restrict__ zpage, float* __restrict__ sums,
    int n, int koff) {
  constexpr int NC = CI / 32;  // 32-ch chunks per offset (2 or 4)
  __shared__ unsigned short Alds[3][128 * 32];

  const int tid = threadIdx.x;
  const int lane = tid & 63;
  const int wave = tid >> 6;
  const int row0 = blockIdx.x * 128;
  const int wrow = (wave >> 1) * 64;
  const int wcol = (wave & 1) * 64;
  const int m = lane & 15;
  const int q = lane >> 4;
  const int srow0 = wave * 16 + (lane >> 2);
  const int sl = lane & 3;

  frag_cd acc[4][4];
#pragma unroll
  for (int i = 0; i < 4; ++i)
#pragma unroll
    for (int j = 0; j < 4; ++j) acc[i][j] = (frag_cd){0.f, 0.f, 0.f, 0.f};

  frag_ab bA[4], bB[4];
  int idxc[2], idxn[2];

  auto load_idx = [&](int ko, int (&dst)[2]) {
#pragma unroll
    for (int i = 0; i < 2; ++i) {
      const int grow = row0 + srow0 + i * 64;
      int v = -1;
      if (grow < n) v = GATHER ? nbr[(size_t)ko * n + grow] : grow;
      dst[i] = v;
    }
  };
  auto stageA = [&](int buf, int ko, int kc, const int (&idx)[2]) {
#pragma unroll
    for (int i = 0; i < 2; ++i) {
      const int row = srow0 + i * 64;
      const int g = sl ^ ((row >> 1) & 3);
      const unsigned short* ga =
          (idx[i] >= 0) ? X + (size_t)idx[i] * CI + kc * 32 + g * 8 : zpage;
      gld16(ga, &Alds[buf][(i * 64 + wave * 16) * 32]);
    }
  };
  // Wt layout: [ko*NC+kc][q][co][8] -> slab 4096 elems per (ko,kc)
  auto loadB = [&](frag_ab (&b)[4], int ko, int kc) {
    const unsigned short* base =
        Wt + (size_t)(ko * NC + kc) * 4096 + q * 1024 + m * 8;
#pragma unroll
    for (int j = 0; j < 4; ++j)
      b[j] = *(const frag_ab*)(base + (wcol + 16 * j) * 8);
  };
  auto do_mfma = [&](int buf, frag_ab (&b)[4]) {
    frag_ab a[4];
#pragma unroll
    for (int i = 0; i < 4; ++i) {
      const int row = wrow + 16 * i + m;
      a[i] = *(const frag_ab*)(&Alds[buf][row * 32 + (q ^ ((row >> 1) & 3)) * 8]);
    }
#pragma unroll
    for (int i = 0; i < 4; ++i)
#pragma unroll
      for (int j = 0; j < 4; ++j)
        acc[i][j] = __builtin_amdgcn_mfma_f32_16x16x32_bf16(a[i], b[j],
                                                            acc[i][j], 0, 0, 0);
  };

  const int T = koff * NC;  // even, >= 2
  load_idx(0, idxc);
  if (koff > 1) load_idx(1, idxn);
  stageA(0, 0, 0, idxc);
  stageA(1, 0, 1, idxc);  // chunk 1 = (ko 0, kc 1) since NC >= 2
  loadB(bA, 0, 0);

  int bufc = 0;
  auto body = [&](int t, frag_ab (&bcur)[4], frag_ab (&bnxt)[4]) {
    asm volatile("s_waitcnt vmcnt(6)" ::: "memory");
    __builtin_amdgcn_s_barrier();
    const int s = t + 2;
    if (s < T && GATHER) {
      const int kos = s / NC;
      if ((s & (NC - 1)) == 0) {  // staging enters a new offset
        idxc[0] = idxn[0];
        idxc[1] = idxn[1];
        if (kos + 1 < koff) load_idx(kos + 1, idxn);
      }
    }
    const int u = t + 1;
    if (u < T) loadB(bnxt, u / NC, u & (NC - 1));
    if (s < T) {
      int bufs = bufc + 2; if (bufs >= 3) bufs -= 3;
      stageA(bufs, s / NC, s & (NC - 1), idxc);
    }
    do_mfma(bufc, bcur);
    if (++bufc == 3) bufc = 0;
  };

  for (int t = 0; t + 3 < T; t += 2) {
    body(t, bA, bB);
    body(t + 1, bB, bA);
  }
  body(T - 2, bA, bB);
  asm volatile("s_waitcnt vmcnt(0)" ::: "memory");
  __builtin_amdgcn_s_barrier();
  do_mfma(bufc, bB);

  // ---- fused BN stats: per-channel sum/sumsq of fp32 acc over block rows --
#pragma unroll
  for (int j = 0; j < 4; ++j) {
    float s = 0.f, qq = 0.f;
#pragma unroll
    for (int i = 0; i < 4; ++i)
#pragma unroll
      for (int r = 0; r < 4; ++r) {
        float v = acc[i][j][r];
        s += v; qq += v * v;
      }
    s += __shfl_xor(s, 16); s += __shfl_xor(s, 32);
    qq += __shfl_xor(qq, 16); qq += __shfl_xor(qq, 32);
    if (lane < 16) {
      const int col = wcol + 16 * j + lane;
      atomicAdd(&sums[col], s);
      atomicAdd(&sums[COUT + col], qq);
    }
  }

  // ---- epilogue: C/D layout col=lane&15, row=(lane>>4)*4+reg ----
#pragma unroll
  for (int i = 0; i < 4; ++i) {
#pragma unroll
    for (int r = 0; r < 4; ++r) {
      const int grow = row0 + wrow + 16 * i + q * 4 + r;
      if (grow < n) {
#pragma unroll
        for (int j = 0; j < 4; ++j) {
          const int gcol = wcol + 16 * j + m;
          if (OF32)
            ((float*)Yv)[(size_t)grow * COUT + gcol] = acc[i][j][r];
          else
            ((unsigned short*)Yv)[(size_t)grow * COUT + gcol] = f2bf(acc[i][j][r]);
        }
      }
    }
  }
}

// fp32 -> bf16, 8 per thread
__global__ void convert_kernel(const float* __restrict__ src,
                               unsigned short* __restrict__ dst, int total8) {
  int gid = blockIdx.x * 256 + threadIdx.x;
  if (gid >= total8) return;
  const float* s = src + (size_t)gid * 8;
  float4 lo = *(const float4*)s;
  float4 hi = *(const float4*)(s + 4);
  uint4 r;
  r.x = (unsigned)f2bf(lo.x) | ((unsigned)f2bf(lo.y) << 16);
  r.y = (unsigned)f2bf(lo.z) | ((unsigned)f2bf(lo.w) << 16);
  r.z = (unsigned)f2bf(hi.x) | ((unsigned)f2bf(hi.y) << 16);
  r.w = (unsigned)f2bf(hi.z) | ((unsigned)f2bf(hi.w) << 16);
  *(uint4*)(dst + (size_t)gid * 8) = r;
}

// dst[((ko*nc+kc)*4+q)*1024 + co*8 + e] (bf16) = src[ko][kc*32+q*8+e][co]
// (co == 128 assumed)
__global__ void transpose_w(const float* __restrict__ src,
                            unsigned short* __restrict__ dst, int koff,
                            int ci) {
  int gid = blockIdx.x * blockDim.x + threadIdx.x;
  int total = koff * ci * 128;
  if (gid >= total) return;
  int e = gid & 7;
  int co = (gid >> 3) & 127;
  int qq = (gid >> 10) & 3;
  int slab = gid >> 12;
  int nc = ci >> 5;
  int ko = slab / nc;
  int kc = slab - ko * nc;
  int cin = kc * 32 + qq * 8 + e;
  dst[gid] = f2bf(src[((size_t)ko * ci + cin) * 128 + co]);
}

__global__ void finalize_kernel(const float* __restrict__ sums,
                                const float* __restrict__ gamma,
                                const float* __restrict__ beta,
                                float* __restrict__ scale,
                                float* __restrict__ shift, int n) {
  int c = threadIdx.x;
  float inv_n = 1.f / (float)n;
  float mean = sums[c] * inv_n;
  float var = sums[COUT + c] * inv_n - mean * mean;
  float sc = gamma[c] * rsqrtf(var + EPS);
  scale[c] = sc;
  shift[c] = beta[c] - mean * sc;
}

// in-place bf16 x = relu(x*scale + shift), 8 bf16 per thread
__global__ void norm_relu_kernel(unsigned short* __restrict__ x,
                                 const float* __restrict__ scale,
                                 const float* __restrict__ shift, int total8) {
  int gid = blockIdx.x * 256 + threadIdx.x;
  if (gid >= total8) return;
  size_t i = (size_t)gid * 8;
  int c0 = (int)(i & 127);
  uint4 v = *(const uint4*)(x + i);
  unsigned int w[4] = {v.x, v.y, v.z, v.w};
  unsigned int wo[4];
#pragma unroll
  for (int e = 0; e < 4; ++e) {
    int c = c0 + 2 * e;
    float f0 = bf2f((unsigned short)(w[e] & 0xffffu));
    float f1 = bf2f((unsigned short)(w[e] >> 16));
    f0 = fmaxf(f0 * scale[c] + shift[c], 0.f);
    f1 = fmaxf(f1 * scale[c + 1] + shift[c + 1], 0.f);
    wo[e] = (unsigned int)f2bf(f0) | ((unsigned int)f2bf(f1) << 16);
  }
  *(uint4*)(x + i) = make_uint4(wo[0], wo[1], wo[2], wo[3]);
}

// out(fp32, in-place on h2) = relu(h2*scale2+shift2 + s*scaled+shiftd)
__global__ void final_kernel(float* __restrict__ h2,
                             const unsigned short* __restrict__ s,
                             const float* __restrict__ scale2,
                             const float* __restrict__ shift2,
                             const float* __restrict__ scaled,
                             const float* __restrict__ shiftd, int total4) {
  int gid = blockIdx.x * 256 + threadIdx.x;
  if (gid >= total4) return;
  size_t i = (size_t)gid * 4;
  int c = (int)(i & 127);
  float4 a = *(const float4*)(h2 + i);
  uint2 sv = *(const uint2*)(s + i);
  float b0 = bf2f((unsigned short)(sv.x & 0xffffu));
  float b1 = bf2f((unsigned short)(sv.x >> 16));
  float b2 = bf2f((unsigned short)(sv.y & 0xffffu));
  float b3 = bf2f((unsigned short)(sv.y >> 16));
  float4 o;
  o.x = fmaxf(a.x * scale2[c] + shift2[c] + b0 * scaled[c] + shiftd[c], 0.f);
  o.y = fmaxf(a.y * scale2[c + 1] + shift2[c + 1] + b1 * scaled[c + 1] + shiftd[c + 1], 0.f);
  o.z = fmaxf(a.z * scale2[c + 2] + shift2[c + 2] + b2 * scaled[c + 2] + shiftd[c + 2], 0.f);
  o.w = fmaxf(a.w * scale2[c + 3] + shift2[c + 3] + b3 * scaled[c + 3] + shiftd[c + 3], 0.f);
  *(float4*)(h2 + i) = o;
}

extern "C" void kernel_launch(void* const* d_in, const int* in_sizes, int n_in,
                              void* d_out, int out_size, void* d_ws,
                              size_t ws_size, hipStream_t stream) {
  (void)n_in; (void)out_size; (void)ws_size;
  const float* feats = (const float*)d_in[0];
  const int* nbr1 = (const int*)d_in[1];
  const int* nbr2 = (const int*)d_in[2];
  const float* W1 = (const float*)d_in[3];
  const float* W2 = (const float*)d_in[4];
  const float* Wd = (const float*)d_in[5];
  const float* g1 = (const float*)d_in[6];
  const float* b1 = (const float*)d_in[7];
  const float* g2 = (const float*)d_in[8];
  const float* b2 = (const float*)d_in[9];
  const float* gd = (const float*)d_in[10];
  const float* bd = (const float*)d_in[11];

  const int n = in_sizes[0] / CIN;  // 200000

  // ws layout (known-good footprint):
  //   Wt1[442368] Wt2[884736] Wdt[16384] h1_bf16[51.2e6] sX_bf16[51.2e6]
  //   stats/scales [8 KB] zpage[256]
  char* ws = (char*)d_ws;
  unsigned short* Wt1 = (unsigned short*)(ws);
  unsigned short* Wt2 = (unsigned short*)(ws + 442368);
  unsigned short* Wdt = (unsigned short*)(ws + 1327104);
  unsigned short* h1 = (unsigned short*)(ws + 1343488);
  unsigned short* sX = (unsigned short*)(ws + 52543488);
  float* sums1 = (float*)(ws + 103743488);
  float* sums2 = sums1 + 2 * COUT;
  float* sumsd = sums1 + 4 * COUT;
  float* scale1 = sums1 + 6 * COUT;
  float* shift1 = scale1 + COUT;
  float* scale2 = scale1 + 2 * COUT;
  float* shift2 = scale1 + 3 * COUT;
  float* scaled = scale1 + 4 * COUT;
  float* shiftd = scale1 + 5 * COUT;
  unsigned short* zpage = (unsigned short*)(ws + 103743488 + 8192);

  float* h2 = (float*)d_out;  // conv2 output -> d_out (fp32)
  // bf16 feats stash: last 25.6 MB of d_out; conv2 clobbers it afterwards
  unsigned short* featsb = (unsigned short*)((char*)d_out + 76800000);

  // zero sums + scales + zero page in one shot
  hipMemsetAsync(sums1, 0, 8192 + 256, stream);

  transpose_w<<<(KOFF * CIN * COUT + 255) / 256, 256, 0, stream>>>(W1, Wt1, KOFF, CIN);
  transpose_w<<<(KOFF * COUT * COUT + 255) / 256, 256, 0, stream>>>(W2, Wt2, KOFF, COUT);
  transpose_w<<<(CIN * COUT + 255) / 256, 256, 0, stream>>>(Wd, Wdt, 1, CIN);

  const int f8 = n * CIN / 8;
  convert_kernel<<<(f8 + 255) / 256, 256, 0, stream>>>(feats, featsb, f8);

  const int mblocks = (n + 127) / 128;
  conv_kernel<CIN, true, false><<<mblocks, 256, 0, stream>>>(featsb, nbr1, Wt1, h1, zpage, sums1, n, KOFF);
  conv_kernel<CIN, false, false><<<mblocks, 256, 0, stream>>>(featsb, nullptr, Wdt, sX, zpage, sumsd, n, 1);

  finalize_kernel<<<1, COUT, 0, stream>>>(sums1, g1, b1, scale1, shift1, n);

  const int total8 = n * COUT / 8;
  norm_relu_kernel<<<(total8 + 255) / 256, 256, 0, stream>>>(h1, scale1, shift1, total8);

  conv_kernel<COUT, true, true><<<mblocks, 256, 0, stream>>>(h1, nbr2, Wt2, h2, zpage, sums2, n, KOFF);

  finalize_kernel<<<1, COUT, 0, stream>>>(sums2, g2, b2, scale2, shift2, n);
  finalize_kernel<<<1, COUT, 0, stream>>>(sumsd, gd, bd, scaled, shiftd, n);

  const int total4 = n * COUT / 4;
  final_kernel<<<(total4 + 255) / 256, 256, 0, stream>>>(h2, sX, scale2, shift2, scaled, shiftd, total4);
}

// Round 7
// 675.963 us; speedup vs baseline: 2.4013x; 1.0296x over previous
//
#include <hip/hip_runtime.h>
#include <stdint.h>

#define KOFF 27
#define CIN 64
#define COUT 128
#define EPS 1e-5f

using frag_ab = __attribute__((ext_vector_type(8))) short;
using frag_cd = __attribute__((ext_vector_type(4))) float;

__device__ __forceinline__ float bf2f(unsigned short u) {
  union { unsigned int i; float f; } x; x.i = ((unsigned int)u) << 16; return x.f;
}
__device__ __forceinline__ unsigned short f2bf(float f) {
  union { float f; unsigned int i; } x; x.f = f;
  unsigned int u = x.i;
  u += 0x7fffu + ((u >> 16) & 1u);   // round-to-nearest-even
  return (unsigned short)(u >> 16);
}

// async global->LDS, 16 B per lane; LDS dest = wave-uniform base + lane*16
__device__ __forceinline__ void gld16(const void* gptr, void* lptr) {
  __builtin_amdgcn_global_load_lds(
      (const __attribute__((address_space(1))) unsigned int*)gptr,
      (__attribute__((address_space(3))) unsigned int*)lptr, 16, 0, 0);
}

// ---------------------------------------------------------------------------
// Gather-GEMM (unchanged from round 6): Y[row] = sum_k X[nbr[k][row]] @ W[k].
// A: global_load_lds, triple-buffered 3x8 KB ring. B: register double-buffer
// from slab layout [ko*NC+kc][q][co][8]. vmcnt(6) partial waits. Fused BN
// stats via zero-page trick + atomics.
// ---------------------------------------------------------------------------
template <int CI, bool GATHER, bool OF32>
__global__ __launch_bounds__(256, 3) void conv_kernel(
    const unsigned short* __restrict__ X, const int* __restrict__ nbr,
    const unsigned short* __restrict__ Wt, void* __restrict__ Yv,
    const unsigned short* __restrict__ zpage, float* __restrict__ sums,
    int n, int koff) {
  constexpr int NC = CI / 32;  // 32-ch chunks per offset (2 or 4)
  __shared__ unsigned short Alds[3][128 * 32];

  const int tid = threadIdx.x;
  const int lane = tid & 63;
  const int wave = tid >> 6;
  const int row0 = blockIdx.x * 128;
  const int wrow = (wave >> 1) * 64;
  const int wcol = (wave & 1) * 64;
  const int m = lane & 15;
  const int q = lane >> 4;
  const int srow0 = wave * 16 + (lane >> 2);
  const int sl = lane & 3;

  frag_cd acc[4][4];
#pragma unroll
  for (int i = 0; i < 4; ++i)
#pragma unroll
    for (int j = 0; j < 4; ++j) acc[i][j] = (frag_cd){0.f, 0.f, 0.f, 0.f};

  frag_ab bA[4], bB[4];
  int idxc[2], idxn[2];

  auto load_idx = [&](int ko, int (&dst)[2]) {
#pragma unroll
    for (int i = 0; i < 2; ++i) {
      const int grow = row0 + srow0 + i * 64;
      int v = -1;
      if (grow < n) v = GATHER ? nbr[(size_t)ko * n + grow] : grow;
      dst[i] = v;
    }
  };
  auto stageA = [&](int buf, int ko, int kc, const int (&idx)[2]) {
#pragma unroll
    for (int i = 0; i < 2; ++i) {
      const int row = srow0 + i * 64;
      const int g = sl ^ ((row >> 1) & 3);
      const unsigned short* ga =
          (idx[i] >= 0) ? X + (size_t)idx[i] * CI + kc * 32 + g * 8 : zpage;
      gld16(ga, &Alds[buf][(i * 64 + wave * 16) * 32]);
    }
  };
  auto loadB = [&](frag_ab (&b)[4], int ko, int kc) {
    const unsigned short* base =
        Wt + (size_t)(ko * NC + kc) * 4096 + q * 1024 + m * 8;
#pragma unroll
    for (int j = 0; j < 4; ++j)
      b[j] = *(const frag_ab*)(base + (wcol + 16 * j) * 8);
  };
  auto do_mfma = [&](int buf, frag_ab (&b)[4]) {
    frag_ab a[4];
#pragma unroll
    for (int i = 0; i < 4; ++i) {
      const int row = wrow + 16 * i + m;
      a[i] = *(const frag_ab*)(&Alds[buf][row * 32 + (q ^ ((row >> 1) & 3)) * 8]);
    }
#pragma unroll
    for (int i = 0; i < 4; ++i)
#pragma unroll
      for (int j = 0; j < 4; ++j)
        acc[i][j] = __builtin_amdgcn_mfma_f32_16x16x32_bf16(a[i], b[j],
                                                            acc[i][j], 0, 0, 0);
  };

  const int T = koff * NC;  // even, >= 2
  load_idx(0, idxc);
  if (koff > 1) load_idx(1, idxn);
  stageA(0, 0, 0, idxc);
  stageA(1, 0, 1, idxc);
  loadB(bA, 0, 0);

  int bufc = 0;
  auto body = [&](int t, frag_ab (&bcur)[4], frag_ab (&bnxt)[4]) {
    asm volatile("s_waitcnt vmcnt(6)" ::: "memory");
    __builtin_amdgcn_s_barrier();
    const int s = t + 2;
    if (s < T && GATHER) {
      const int kos = s / NC;
      if ((s & (NC - 1)) == 0) {
        idxc[0] = idxn[0];
        idxc[1] = idxn[1];
        if (kos + 1 < koff) load_idx(kos + 1, idxn);
      }
    }
    const int u = t + 1;
    if (u < T) loadB(bnxt, u / NC, u & (NC - 1));
    if (s < T) {
      int bufs = bufc + 2; if (bufs >= 3) bufs -= 3;
      stageA(bufs, s / NC, s & (NC - 1), idxc);
    }
    do_mfma(bufc, bcur);
    if (++bufc == 3) bufc = 0;
  };

  for (int t = 0; t + 3 < T; t += 2) {
    body(t, bA, bB);
    body(t + 1, bB, bA);
  }
  body(T - 2, bA, bB);
  asm volatile("s_waitcnt vmcnt(0)" ::: "memory");
  __builtin_amdgcn_s_barrier();
  do_mfma(bufc, bB);

  // fused BN stats
#pragma unroll
  for (int j = 0; j < 4; ++j) {
    float s = 0.f, qq = 0.f;
#pragma unroll
    for (int i = 0; i < 4; ++i)
#pragma unroll
      for (int r = 0; r < 4; ++r) {
        float v = acc[i][j][r];
        s += v; qq += v * v;
      }
    s += __shfl_xor(s, 16); s += __shfl_xor(s, 32);
    qq += __shfl_xor(qq, 16); qq += __shfl_xor(qq, 32);
    if (lane < 16) {
      const int col = wcol + 16 * j + lane;
      atomicAdd(&sums[col], s);
      atomicAdd(&sums[COUT + col], qq);
    }
  }

  // epilogue: C/D layout col=lane&15, row=(lane>>4)*4+reg
#pragma unroll
  for (int i = 0; i < 4; ++i) {
#pragma unroll
    for (int r = 0; r < 4; ++r) {
      const int grow = row0 + wrow + 16 * i + q * 4 + r;
      if (grow < n) {
#pragma unroll
        for (int j = 0; j < 4; ++j) {
          const int gcol = wcol + 16 * j + m;
          if (OF32)
            ((float*)Yv)[(size_t)grow * COUT + gcol] = acc[i][j][r];
          else
            ((unsigned short*)Yv)[(size_t)grow * COUT + gcol] = f2bf(acc[i][j][r]);
        }
      }
    }
  }
}

// ---------------------------------------------------------------------------
// Fused: fp32->bf16 convert of feats (writes featsb) + skip GEMM feats@Wd
// (B transposed from fp32 Wd on the fly) + fused skip BN stats.
// Block = 128 rows. A staged once in LDS (2 chunks of 32 ch, same swizzled
// layout as conv_kernel). No pipeline needed: sequential reads, 1563 blocks.
// ---------------------------------------------------------------------------
__global__ __launch_bounds__(256, 2) void convskip_kernel(
    const float* __restrict__ feats, const float* __restrict__ Wd,
    unsigned short* __restrict__ featsb, unsigned short* __restrict__ sX,
    float* __restrict__ sums, int n) {
  __shared__ unsigned short Alds[2][128 * 32];
  const int tid = threadIdx.x;
  const int lane = tid & 63;
  const int wave = tid >> 6;
  const int row0 = blockIdx.x * 128;
  const int wrow = (wave >> 1) * 64;
  const int wcol = (wave & 1) * 64;
  const int m = lane & 15;
  const int q = lane >> 4;

  // stage A (+ write featsb): 1024 units = (kc, row, s)
#pragma unroll
  for (int c = 0; c < 4; ++c) {
    int u = c * 256 + tid;
    int kc = u >> 9;
    int v = u & 511;
    int row = v >> 2;
    int s = v & 3;
    int g = s ^ ((row >> 1) & 3);
    int grow = row0 + row;
    uint4 out = make_uint4(0u, 0u, 0u, 0u);
    if (grow < n) {
      const float* p = feats + (size_t)grow * 64 + kc * 32 + g * 8;
      float4 lo = *(const float4*)p;
      float4 hi = *(const float4*)(p + 4);
      out.x = (unsigned)f2bf(lo.x) | ((unsigned)f2bf(lo.y) << 16);
      out.y = (unsigned)f2bf(lo.z) | ((unsigned)f2bf(lo.w) << 16);
      out.z = (unsigned)f2bf(hi.x) | ((unsigned)f2bf(hi.y) << 16);
      out.w = (unsigned)f2bf(hi.z) | ((unsigned)f2bf(hi.w) << 16);
      *(uint4*)(featsb + (size_t)grow * 64 + kc * 32 + g * 8) = out;
    }
    *(uint4*)(&Alds[kc][row * 32 + s * 8]) = out;
  }
  __syncthreads();

  frag_cd acc[4][4];
#pragma unroll
  for (int i = 0; i < 4; ++i)
#pragma unroll
    for (int j = 0; j < 4; ++j) acc[i][j] = (frag_cd){0.f, 0.f, 0.f, 0.f};

#pragma unroll
  for (int kc = 0; kc < 2; ++kc) {
    frag_ab b[4];
#pragma unroll
    for (int j = 0; j < 4; ++j) {
      const int co = wcol + 16 * j + m;
#pragma unroll
      for (int e = 0; e < 8; ++e)
        b[j][e] = (short)f2bf(Wd[(size_t)(kc * 32 + q * 8 + e) * 128 + co]);
    }
    frag_ab a[4];
#pragma unroll
    for (int i = 0; i < 4; ++i) {
      const int row = wrow + 16 * i + m;
      a[i] = *(const frag_ab*)(&Alds[kc][row * 32 + (q ^ ((row >> 1) & 3)) * 8]);
    }
#pragma unroll
    for (int i = 0; i < 4; ++i)
#pragma unroll
      for (int j = 0; j < 4; ++j)
        acc[i][j] = __builtin_amdgcn_mfma_f32_16x16x32_bf16(a[i], b[j],
                                                            acc[i][j], 0, 0, 0);
  }

  // fused BN stats (tail rows contribute exact zeros)
#pragma unroll
  for (int j = 0; j < 4; ++j) {
    float s = 0.f, qq = 0.f;
#pragma unroll
    for (int i = 0; i < 4; ++i)
#pragma unroll
      for (int r = 0; r < 4; ++r) {
        float v = acc[i][j][r];
        s += v; qq += v * v;
      }
    s += __shfl_xor(s, 16); s += __shfl_xor(s, 32);
    qq += __shfl_xor(qq, 16); qq += __shfl_xor(qq, 32);
    if (lane < 16) {
      const int col = wcol + 16 * j + lane;
      atomicAdd(&sums[col], s);
      atomicAdd(&sums[COUT + col], qq);
    }
  }

#pragma unroll
  for (int i = 0; i < 4; ++i) {
#pragma unroll
    for (int r = 0; r < 4; ++r) {
      const int grow = row0 + wrow + 16 * i + q * 4 + r;
      if (grow < n) {
#pragma unroll
        for (int j = 0; j < 4; ++j)
          sX[(size_t)grow * COUT + wcol + 16 * j + m] = f2bf(acc[i][j][r]);
      }
    }
  }
}

// ---------------------------------------------------------------------------
// prep: zero sums (768 floats) + zpage (64 floats) + Wt1/Wt2 slab transposes.
// slab layout: dst[((ko*nc+kc)*4+q)*1024 + co*8 + e] = bf16(src[ko][kc*32+q*8+e][co])
// ---------------------------------------------------------------------------
__global__ void prep_kernel(const float* __restrict__ W1,
                            const float* __restrict__ W2,
                            unsigned short* __restrict__ Wt1,
                            unsigned short* __restrict__ Wt2,
                            float* __restrict__ zbase,
                            float* __restrict__ zpage) {
  const int NZ = 768 + 64;
  const int NW1 = KOFF * CIN * 128;    // 221184
  const int NW2 = KOFF * COUT * 128;   // 442368
  int gid = blockIdx.x * 256 + threadIdx.x;
  if (gid < NZ) {
    if (gid < 768) zbase[gid] = 0.f; else zpage[gid - 768] = 0.f;
    return;
  }
  gid -= NZ;
  const float* src;
  unsigned short* dst;
  int ci;
  if (gid < NW1) { src = W1; dst = Wt1; ci = CIN; }
  else if (gid < NW1 + NW2) { gid -= NW1; src = W2; dst = Wt2; ci = COUT; }
  else return;
  int e = gid & 7;
  int co = (gid >> 3) & 127;
  int qq = (gid >> 10) & 3;
  int slab = gid >> 12;
  int nc = ci >> 5;
  int ko = slab / nc;
  int kc = slab - ko * nc;
  int cin = kc * 32 + qq * 8 + e;
  dst[gid] = f2bf(src[((size_t)ko * ci + cin) * 128 + co]);
}

// in-place bf16 x = relu(x*scale + shift); finalize fused (per-block LDS)
__global__ void norm_relu_kernel(unsigned short* __restrict__ x,
                                 const float* __restrict__ sums,
                                 const float* __restrict__ gamma,
                                 const float* __restrict__ beta,
                                 int n, int total8) {
  __shared__ float sc[COUT], sh[COUT];
  const int tid = threadIdx.x;
  if (tid < COUT) {
    float inv_n = 1.f / (float)n;
    float mean = sums[tid] * inv_n;
    float var = sums[COUT + tid] * inv_n - mean * mean;
    float s = gamma[tid] * rsqrtf(var + EPS);
    sc[tid] = s;
    sh[tid] = beta[tid] - mean * s;
  }
  __syncthreads();
  int gid = blockIdx.x * 256 + tid;
  if (gid >= total8) return;
  size_t i = (size_t)gid * 8;
  int c0 = (int)(i & 127);
  uint4 v = *(const uint4*)(x + i);
  unsigned int w[4] = {v.x, v.y, v.z, v.w};
  unsigned int wo[4];
#pragma unroll
  for (int e = 0; e < 4; ++e) {
    int c = c0 + 2 * e;
    float f0 = bf2f((unsigned short)(w[e] & 0xffffu));
    float f1 = bf2f((unsigned short)(w[e] >> 16));
    f0 = fmaxf(f0 * sc[c] + sh[c], 0.f);
    f1 = fmaxf(f1 * sc[c + 1] + sh[c + 1], 0.f);
    wo[e] = (unsigned int)f2bf(f0) | ((unsigned int)f2bf(f1) << 16);
  }
  *(uint4*)(x + i) = make_uint4(wo[0], wo[1], wo[2], wo[3]);
}

// out(fp32, in-place on h2) = relu(bn2(h2) + bnd(s)); finalize fused
__global__ void final_kernel(float* __restrict__ h2,
                             const unsigned short* __restrict__ s,
                             const float* __restrict__ sums2,
                             const float* __restrict__ sumsd,
                             const float* __restrict__ g2,
                             const float* __restrict__ b2,
                             const float* __restrict__ gd,
                             const float* __restrict__ bd,
                             int n, int total4) {
  __shared__ float sc2[COUT], sh2[COUT], scd[COUT], shd[COUT];
  const int tid = threadIdx.x;
  if (tid < COUT) {
    float inv_n = 1.f / (float)n;
    float mean = sums2[tid] * inv_n;
    float var = sums2[COUT + tid] * inv_n - mean * mean;
    float sa = g2[tid] * rsqrtf(var + EPS);
    sc2[tid] = sa;
    sh2[tid] = b2[tid] - mean * sa;
    mean = sumsd[tid] * inv_n;
    var = sumsd[COUT + tid] * inv_n - mean * mean;
    float sb = gd[tid] * rsqrtf(var + EPS);
    scd[tid] = sb;
    shd[tid] = bd[tid] - mean * sb;
  }
  __syncthreads();
  int gid = blockIdx.x * 256 + tid;
  if (gid >= total4) return;
  size_t i = (size_t)gid * 4;
  int c = (int)(i & 127);
  float4 a = *(const float4*)(h2 + i);
  uint2 sv = *(const uint2*)(s + i);
  float b0 = bf2f((unsigned short)(sv.x & 0xffffu));
  float b1 = bf2f((unsigned short)(sv.x >> 16));
  float b2f = bf2f((unsigned short)(sv.y & 0xffffu));
  float b3 = bf2f((unsigned short)(sv.y >> 16));
  float4 o;
  o.x = fmaxf(a.x * sc2[c] + sh2[c] + b0 * scd[c] + shd[c], 0.f);
  o.y = fmaxf(a.y * sc2[c + 1] + sh2[c + 1] + b1 * scd[c + 1] + shd[c + 1], 0.f);
  o.z = fmaxf(a.z * sc2[c + 2] + sh2[c + 2] + b2f * scd[c + 2] + shd[c + 2], 0.f);
  o.w = fmaxf(a.w * sc2[c + 3] + sh2[c + 3] + b3 * scd[c + 3] + shd[c + 3], 0.f);
  *(float4*)(h2 + i) = o;
}

extern "C" void kernel_launch(void* const* d_in, const int* in_sizes, int n_in,
                              void* d_out, int out_size, void* d_ws,
                              size_t ws_size, hipStream_t stream) {
  (void)n_in; (void)out_size; (void)ws_size;
  const float* feats = (const float*)d_in[0];
  const int* nbr1 = (const int*)d_in[1];
  const int* nbr2 = (const int*)d_in[2];
  const float* W1 = (const float*)d_in[3];
  const float* W2 = (const float*)d_in[4];
  const float* Wd = (const float*)d_in[5];
  const float* g1 = (const float*)d_in[6];
  const float* b1 = (const float*)d_in[7];
  const float* g2 = (const float*)d_in[8];
  const float* b2 = (const float*)d_in[9];
  const float* gd = (const float*)d_in[10];
  const float* bd = (const float*)d_in[11];

  const int n = in_sizes[0] / CIN;  // 200000

  // ws layout (known-good footprint):
  //   Wt1[442368] Wt2[884736] (hole) h1_bf16[51.2e6] sX_bf16[51.2e6]
  //   sums[3 KB in 8 KB slot] zpage[256]
  char* ws = (char*)d_ws;
  unsigned short* Wt1 = (unsigned short*)(ws);
  unsigned short* Wt2 = (unsigned short*)(ws + 442368);
  unsigned short* h1 = (unsigned short*)(ws + 1343488);
  unsigned short* sX = (unsigned short*)(ws + 52543488);
  float* sums1 = (float*)(ws + 103743488);
  float* sums2 = sums1 + 2 * COUT;
  float* sumsd = sums1 + 4 * COUT;
  unsigned short* zpage = (unsigned short*)(ws + 103743488 + 8192);

  float* h2 = (float*)d_out;  // conv2 output -> d_out (fp32)
  // bf16 feats stash: last 25.6 MB of d_out; conv2 clobbers it afterwards
  unsigned short* featsb = (unsigned short*)((char*)d_out + 76800000);

  const int prep_units = (768 + 64) + KOFF * CIN * 128 + KOFF * COUT * 128;
  prep_kernel<<<(prep_units + 255) / 256, 256, 0, stream>>>(
      W1, W2, Wt1, Wt2, sums1, (float*)zpage);

  const int mblocks = (n + 127) / 128;
  convskip_kernel<<<mblocks, 256, 0, stream>>>(feats, Wd, featsb, sX, sumsd, n);

  conv_kernel<CIN, true, false><<<mblocks, 256, 0, stream>>>(
      featsb, nbr1, Wt1, h1, zpage, sums1, n, KOFF);

  const int total8 = n * COUT / 8;
  norm_relu_kernel<<<(total8 + 255) / 256, 256, 0, stream>>>(h1, sums1, g1, b1, n, total8);

  conv_kernel<COUT, true, true><<<mblocks, 256, 0, stream>>>(
      h1, nbr2, Wt2, h2, zpage, sums2, n, KOFF);

  const int total4 = n * COUT / 4;
  final_kernel<<<(total4 + 255) / 256, 256, 0, stream>>>(
      h2, sX, sums2, sumsd, g2, b2, gd, bd, n, total4);
}